// Round 1
// baseline (426.377 us; speedup 1.0000x reference)
//
#include <hip/hip_runtime.h>
#include <math.h>

// Problem constants
static constexpr int NB    = 2048;  // batch
static constexpr int NPOOL = 512;   // e_prompt_pool_size
static constexpr int NTOPK = 4;     // top_k
static constexpr int NEPL  = 8;     // e_prompt_length
static constexpr int NEMB  = 768;   // emb_d / key_dim
static constexpr int NSLOT = 20;    // K*EPL/2 + GPL/2 = 16 + 4

// ---------------------------------------------------------------------------
// K1: row L2 norms (fp64 reciprocal for rescore/usum/loss, fp32 reciprocal
// for the GEMM epilogue) + fused zero-init of all accumulators (replaces the
// two hipMemsetAsync dispatches). rows 0..NB-1 -> x_querry, NB.. -> e_k,
// last block -> zero-init.
// ---------------------------------------------------------------------------
__global__ __launch_bounds__(256) void norms_kernel(
    const float* __restrict__ xq, const float* __restrict__ ek,
    double* __restrict__ qinv, double* __restrict__ kinv,
    float* __restrict__ rqn, float* __restrict__ rkn,
    double* __restrict__ u, double* __restrict__ lacc,
    int* __restrict__ done, int* __restrict__ counts) {
  int row = blockIdx.x;
  if (row == NB + NPOOL) {  // zero-init block (runs each graph replay)
    for (int i = threadIdx.x; i < NEMB; i += 256) u[i] = 0.0;
    for (int i = threadIdx.x; i < NPOOL; i += 256) counts[i] = 0;
    if (threadIdx.x == 0) { *lacc = 0.0; *done = 0; }
    return;
  }
  const float* src;
  double* dinv;
  float* rdst;
  if (row < NB) { src = xq + (size_t)row * NEMB; dinv = qinv + row; rdst = rqn + row; }
  else          { src = ek + (size_t)(row - NB) * NEMB; dinv = kinv + (row - NB); rdst = rkn + (row - NB); }
  double s = 0.0;
  for (int i = threadIdx.x; i < NEMB; i += 256) {
    double v = (double)src[i];
    s += v * v;
  }
  for (int off = 32; off > 0; off >>= 1) s += __shfl_down(s, off, 64);
  __shared__ double red[4];
  if ((threadIdx.x & 63) == 0) red[threadIdx.x >> 6] = s;
  __syncthreads();
  if (threadIdx.x == 0) {
    double n = sqrt(red[0] + red[1] + red[2] + red[3]);
    double inv = 1.0 / fmax(n, 1e-12);
    *dinv = inv;
    *rdst = (float)inv;
  }
}

// ---------------------------------------------------------------------------
// K2: fp32 cos GEMM (blocks with blockIdx.x < 8, unchanged 64x64 tiling)
// fused with the u-vector accumulation u[j] = sum_b xq[b][j]*qinv[b]
// (blocks with blockIdx.x >= 8 — they fill CUs the 256-block GEMM leaves
// idle). u replaces the colsum kernel: S[p] = (ek[p].u)*kinv[p] analytically.
// ---------------------------------------------------------------------------
__global__ __launch_bounds__(256) void cos_kernel(
    const float* __restrict__ xq, const float* __restrict__ ek,
    const float* __restrict__ rqn, const float* __restrict__ rkn,
    const double* __restrict__ qinv, float* __restrict__ cosm,
    double* __restrict__ u) {
  if (blockIdx.x >= NPOOL / 64) {
    // ---- usum branch: 2*32 = 64 blocks, 32 rows each ----
    int b = (blockIdx.x - NPOOL / 64) * (NB / 64) + blockIdx.y;  // 0..63
    int c0 = threadIdx.x;
    int r0 = b * 32;
    double s0 = 0.0, s1 = 0.0, s2 = 0.0;
    for (int r = r0; r < r0 + 32; r++) {
      double inv = qinv[r];
      const float* xr = xq + (size_t)r * NEMB;
      s0 = fma((double)xr[c0], inv, s0);
      s1 = fma((double)xr[c0 + 256], inv, s1);
      s2 = fma((double)xr[c0 + 512], inv, s2);
    }
    atomicAdd(&u[c0], s0);
    atomicAdd(&u[c0 + 256], s1);
    atomicAdd(&u[c0 + 512], s2);
    return;
  }
  // ---- GEMM branch: cosm[b][p] = (xq[b].ek[p]) * rqn[b] * rkn[p] ----
  __shared__ float As[32][68];
  __shared__ float Bs[32][68];
  const int t = threadIdx.x;
  const int tx = t & 15;   // p-dir, 4 cols each
  const int ty = t >> 4;   // b-dir, 4 rows each
  const int bp = blockIdx.x * 64;
  const int bb = blockIdx.y * 64;
  float acc[4][4] = {};
  for (int k0 = 0; k0 < NEMB; k0 += 32) {
#pragma unroll
    for (int uu = 0; uu < 2; uu++) {
      int uidx = t + uu * 256;       // 0..511
      int m = uidx >> 3;             // 0..63
      int k4 = (uidx & 7) * 4;       // 0..28
      float4 a = *(const float4*)(xq + (size_t)(bb + m) * NEMB + k0 + k4);
      float4 bvv = *(const float4*)(ek + (size_t)(bp + m) * NEMB + k0 + k4);
      As[k4 + 0][m] = a.x; As[k4 + 1][m] = a.y; As[k4 + 2][m] = a.z; As[k4 + 3][m] = a.w;
      Bs[k4 + 0][m] = bvv.x; Bs[k4 + 1][m] = bvv.y; Bs[k4 + 2][m] = bvv.z; Bs[k4 + 3][m] = bvv.w;
    }
    __syncthreads();
#pragma unroll
    for (int kk = 0; kk < 32; kk++) {
      float4 av = *(const float4*)&As[kk][ty * 4];
      float4 bv = *(const float4*)&Bs[kk][tx * 4];
      acc[0][0] = fmaf(av.x, bv.x, acc[0][0]); acc[0][1] = fmaf(av.x, bv.y, acc[0][1]);
      acc[0][2] = fmaf(av.x, bv.z, acc[0][2]); acc[0][3] = fmaf(av.x, bv.w, acc[0][3]);
      acc[1][0] = fmaf(av.y, bv.x, acc[1][0]); acc[1][1] = fmaf(av.y, bv.y, acc[1][1]);
      acc[1][2] = fmaf(av.y, bv.z, acc[1][2]); acc[1][3] = fmaf(av.y, bv.w, acc[1][3]);
      acc[2][0] = fmaf(av.z, bv.x, acc[2][0]); acc[2][1] = fmaf(av.z, bv.y, acc[2][1]);
      acc[2][2] = fmaf(av.z, bv.z, acc[2][2]); acc[2][3] = fmaf(av.z, bv.w, acc[2][3]);
      acc[3][0] = fmaf(av.w, bv.x, acc[3][0]); acc[3][1] = fmaf(av.w, bv.y, acc[3][1]);
      acc[3][2] = fmaf(av.w, bv.z, acc[3][2]); acc[3][3] = fmaf(av.w, bv.w, acc[3][3]);
    }
    __syncthreads();
  }
  float4 rk = *(const float4*)&rkn[bp + tx * 4];
#pragma unroll
  for (int i = 0; i < 4; i++) {
    float rq = rqn[bb + ty * 4 + i];
    float4 cv;
    cv.x = acc[i][0] * rq * rk.x;
    cv.y = acc[i][1] * rq * rk.y;
    cv.z = acc[i][2] * rq * rk.z;
    cv.w = acc[i][3] * rq * rk.w;
    *(float4*)(cosm + (size_t)(bb + ty * 4 + i) * NPOOL + bp + tx * 4) = cv;
  }
}

// ---------------------------------------------------------------------------
// K3: fused top-4 + gather. One block per row. Wave 0: fp32 top-8 shortlist
// (sort-8 + butterfly merge), fp64 rescore, top-4 select, counts atomics,
// indices -> LDS. Then all 4 waves gather Pk/Pv (float4 coalesced) and copy
// x_block. Removes the kidx global round-trip and one full-GPU sync: gather
// of early rows overlaps topk of later rows across resident blocks.
// ---------------------------------------------------------------------------
__device__ __forceinline__ bool btf(float av, int ai, float bv, int bi) {
  return (av > bv) || (av == bv && ai < bi);
}
__device__ __forceinline__ bool btd(double av, int ai, double bv, int bi) {
  return (av > bv) || (av == bv && ai < bi);
}
#define CE(a, b)                                                        \
  do {                                                                  \
    if (!btf(v[a], vi[a], v[b], vi[b])) {                               \
      float tv = v[a]; v[a] = v[b]; v[b] = tv;                          \
      int ti = vi[a]; vi[a] = vi[b]; vi[b] = ti;                        \
    }                                                                   \
  } while (0)

__global__ __launch_bounds__(256) void topk_gather_kernel(
    const float* __restrict__ cosm, const float* __restrict__ xq,
    const float* __restrict__ ek, const double* __restrict__ qinv,
    const double* __restrict__ kinv, const float* __restrict__ e_p,
    const float* __restrict__ g_p, const float* __restrict__ x_block,
    int* __restrict__ counts, float* __restrict__ Pk, float* __restrict__ Pv,
    float* __restrict__ out_xb) {
  const int row = blockIdx.x;
  __shared__ int sidx[4];
  const int wave = threadIdx.x >> 6, lane = threadIdx.x & 63;
  if (wave == 0) {
    const float* crow = cosm + (size_t)row * NPOOL;
    float v[8]; int vi[8];
#pragma unroll
    for (int j = 0; j < 8; j++) {
      int p = j * 64 + lane;
      v[j] = crow[p];
      vi[j] = p;
    }
    // sort-8 descending (Batcher odd-even mergesort, 19 CEs)
    CE(0,1); CE(2,3); CE(4,5); CE(6,7);
    CE(0,2); CE(1,3); CE(4,6); CE(5,7);
    CE(1,2); CE(5,6);
    CE(0,4); CE(1,5); CE(2,6); CE(3,7);
    CE(2,4); CE(3,5);
    CE(1,2); CE(3,4); CE(5,6);
    // butterfly merge: after 6 rounds every lane holds the global top-8
#pragma unroll
    for (int off = 1; off < 64; off <<= 1) {
      float ov[8]; int oi[8];
#pragma unroll
      for (int m = 0; m < 8; m++) {
        ov[m] = __shfl_xor(v[m], off, 64);
        oi[m] = __shfl_xor(vi[m], off, 64);
      }
#pragma unroll
      for (int m = 0; m < 8; m++) {
        if (!btf(v[m], vi[m], ov[7 - m], oi[7 - m])) { v[m] = ov[7 - m]; vi[m] = oi[7 - m]; }
      }
      CE(0,4); CE(1,5); CE(2,6); CE(3,7);
      CE(0,2); CE(1,3); CE(4,6); CE(5,7);
      CE(0,1); CE(2,3); CE(4,5); CE(6,7);
    }
    // fp64 rescore of the 8 candidates (wave-cooperative dot, 12 elems/lane)
    const float* xrow = xq + (size_t)row * NEMB;
    double xr[12];
#pragma unroll
    for (int e = 0; e < 12; e++) xr[e] = (double)xrow[lane * 12 + e];
    double qi = qinv[row];
    double cand[8];
#pragma unroll
    for (int c = 0; c < 8; c++) {
      int pi = vi[c];
      const float* kb = ek + (size_t)pi * NEMB + lane * 12;
      double s = 0.0;
#pragma unroll
      for (int e = 0; e < 12; e++) s = fma(xr[e], (double)kb[e], s);
#pragma unroll
      for (int off = 1; off < 64; off <<= 1) s += __shfl_xor(s, off, 64);
      cand[c] = s * qi * kinv[pi];
    }
    // top-4 of 8 by fp64 (uniform across lanes; lane 0 publishes)
    bool used[8] = {false, false, false, false, false, false, false, false};
#pragma unroll
    for (int m = 0; m < NTOPK; m++) {
      int best = -1;
#pragma unroll
      for (int c = 0; c < 8; c++) {
        if (!used[c] && (best < 0 || btd(cand[c], vi[c], cand[best], vi[best]))) best = c;
      }
      used[best] = true;
      if (lane == 0) {
        sidx[m] = vi[best];
        atomicAdd(&counts[vi[best]], 1);
      }
    }
  }
  __syncthreads();
  // ---- gather phase: all 4 waves ----
  float4* dk = (float4*)(Pk + (size_t)row * NSLOT * NEMB);
  float4* dv = (float4*)(Pv + (size_t)row * NSLOT * NEMB);
  const int R = NEMB / 4;  // 192 float4 per row
  for (int uidx = threadIdx.x; uidx < NSLOT * R; uidx += 256) {
    int s = uidx / R;
    int r = uidx - s * R;
    const float4* sk;
    const float4* sv;
    if (s < 16) {
      int pi = sidx[s >> 2];
      int tt = s & 3;
      const float* basek = e_p + ((size_t)pi * NEPL + tt) * NEMB;
      sk = (const float4*)basek;
      sv = (const float4*)(basek + 4 * NEMB);
    } else {
      sk = (const float4*)(g_p + (size_t)(s - 16) * NEMB);
      sv = (const float4*)(g_p + (size_t)(s - 16 + 4) * NEMB);
    }
    dk[uidx] = sk[r];
    dv[uidx] = sv[r];
  }
  // fused x_block passthrough (dst only 4B-aligned -> scalar)
  for (int i = threadIdx.x; i < NEMB; i += 256)
    out_xb[(size_t)row * NEMB + i] = x_block[(size_t)row * NEMB + i];
}
#undef CE

// ---------------------------------------------------------------------------
// K4: loss = 1 - (u . w)/(B*B*K),  w[j] = sum_p counts[p]*kinv[p]*ek[p][j].
// 3 blocks of 256 columns; device-scope atomics + done-counter finish.
// Block 0 also emits counts as float.
// ---------------------------------------------------------------------------
__global__ __launch_bounds__(256) void loss_kernel(
    const float* __restrict__ ek, const double* __restrict__ kinv,
    const double* __restrict__ u, const int* __restrict__ counts,
    double* __restrict__ lacc, int* __restrict__ done,
    float* __restrict__ out_loss, float* __restrict__ out_counts) {
  __shared__ double tp[NPOOL];
  for (int p = threadIdx.x; p < NPOOL; p += 256) {
    int c = counts[p];
    tp[p] = (double)c * kinv[p];
    if (blockIdx.x == 0) out_counts[p] = (float)c;
  }
  __syncthreads();
  const int j = blockIdx.x * 256 + threadIdx.x;  // 0..767
  double m = 0.0;
  for (int p = 0; p < NPOOL; p++) m = fma(tp[p], (double)ek[(size_t)p * NEMB + j], m);
  double part = m * u[j];
  for (int off = 32; off > 0; off >>= 1) part += __shfl_down(part, off, 64);
  __shared__ double red[4];
  if ((threadIdx.x & 63) == 0) red[threadIdx.x >> 6] = part;
  __syncthreads();
  if (threadIdx.x == 0) {
    double tot = red[0] + red[1] + red[2] + red[3];
    atomicAdd(lacc, tot);
    __threadfence();
    int d = atomicAdd(done, 1);
    if (d == 2) {  // last block finishes
      double total = atomicAdd(lacc, 0.0);  // device-scope read
      *out_loss = (float)(1.0 - total / (double)((long long)NB * NB * NTOPK));
    }
  }
}

extern "C" void kernel_launch(void* const* d_in, const int* in_sizes, int n_in,
                              void* d_out, int out_size, void* d_ws, size_t ws_size,
                              hipStream_t stream) {
  const float* x_querry = (const float*)d_in[0];
  const float* x_block  = (const float*)d_in[1];
  const float* e_k      = (const float*)d_in[2];
  const float* e_p      = (const float*)d_in[3];
  const float* g_p      = (const float*)d_in[4];
  // d_in[5] = l (scalar 0) — both E- and G-branches always taken.

  // Workspace layout (~4.3 MB)
  double* qinv   = (double*)d_ws;                     // 2048
  double* kinv   = qinv + NB;                         // 512
  double* u      = kinv + NPOOL;                      // 768
  double* lacc   = u + NEMB;                          // 1
  int*    done   = (int*)(lacc + 1);                  // 1 (+1 pad, keeps 8B align)
  float*  rqn    = (float*)(done + 2);                // 2048
  float*  rkn    = rqn + NB;                          // 512
  float*  cosm   = rkn + NPOOL;                       // 2048*512 (16B-aligned)
  int*    counts = (int*)(cosm + (size_t)NB * NPOOL); // 512

  // Output layout (floats): Pk | Pv | loss | counts | x_block
  float* out        = (float*)d_out;
  float* Pk         = out;
  float* Pv         = Pk + (size_t)NB * NSLOT * NEMB;
  float* out_loss   = Pv + (size_t)NB * NSLOT * NEMB;
  float* out_counts = out_loss + 1;
  float* out_xb     = out_counts + NPOOL;

  // 4 dispatches total (was 8: 2 memsets + 6 kernels).
  norms_kernel<<<NB + NPOOL + 1, 256, 0, stream>>>(
      x_querry, e_k, qinv, kinv, rqn, rkn, u, lacc, done, counts);
  cos_kernel<<<dim3(NPOOL / 64 + 2, NB / 64), 256, 0, stream>>>(
      x_querry, e_k, rqn, rkn, qinv, cosm, u);
  topk_gather_kernel<<<NB, 256, 0, stream>>>(
      cosm, x_querry, e_k, qinv, kinv, e_p, g_p, x_block, counts, Pk, Pv, out_xb);
  loss_kernel<<<3, 256, 0, stream>>>(
      e_k, kinv, u, counts, lacc, done, out_loss, out_counts);
}

// Round 2
// 413.685 us; speedup vs baseline: 1.0307x; 1.0307x over previous
//
#include <hip/hip_runtime.h>
#include <math.h>

// Problem constants
static constexpr int NB    = 2048;  // batch
static constexpr int NPOOL = 512;   // e_prompt_pool_size
static constexpr int NTOPK = 4;     // top_k
static constexpr int NEPL  = 8;     // e_prompt_length
static constexpr int NEMB  = 768;   // emb_d / key_dim
static constexpr int NSLOT = 20;    // K*EPL/2 + GPL/2 = 16 + 4

// ---------------------------------------------------------------------------
// K1: row L2 norms (fp64 reciprocal for rescore/usum/loss, fp32 reciprocal
// for the GEMM epilogue) + fused zero-init of all accumulators (replaces the
// two hipMemsetAsync dispatches). rows 0..NB-1 -> x_querry, NB.. -> e_k,
// last block -> zero-init.
// ---------------------------------------------------------------------------
__global__ __launch_bounds__(256) void norms_kernel(
    const float* __restrict__ xq, const float* __restrict__ ek,
    double* __restrict__ qinv, double* __restrict__ kinv,
    float* __restrict__ rqn, float* __restrict__ rkn,
    double* __restrict__ u, double* __restrict__ lacc,
    int* __restrict__ done, int* __restrict__ counts) {
  int row = blockIdx.x;
  if (row == NB + NPOOL) {  // zero-init block (runs each graph replay)
    for (int i = threadIdx.x; i < NEMB; i += 256) u[i] = 0.0;
    for (int i = threadIdx.x; i < NPOOL; i += 256) counts[i] = 0;
    if (threadIdx.x == 0) { *lacc = 0.0; *done = 0; }
    return;
  }
  const float* src;
  double* dinv;
  float* rdst;
  if (row < NB) { src = xq + (size_t)row * NEMB; dinv = qinv + row; rdst = rqn + row; }
  else          { src = ek + (size_t)(row - NB) * NEMB; dinv = kinv + (row - NB); rdst = rkn + (row - NB); }
  double s = 0.0;
  for (int i = threadIdx.x; i < NEMB; i += 256) {
    double v = (double)src[i];
    s += v * v;
  }
  for (int off = 32; off > 0; off >>= 1) s += __shfl_down(s, off, 64);
  __shared__ double red[4];
  if ((threadIdx.x & 63) == 0) red[threadIdx.x >> 6] = s;
  __syncthreads();
  if (threadIdx.x == 0) {
    double n = sqrt(red[0] + red[1] + red[2] + red[3]);
    double inv = 1.0 / fmax(n, 1e-12);
    *dinv = inv;
    *rdst = (float)inv;
  }
}

// ---------------------------------------------------------------------------
// K2: fp32 cos GEMM (blocks with blockIdx.x < 8, unchanged 64x64 tiling)
// fused with the u-vector accumulation u[j] = sum_b xq[b][j]*qinv[b]
// (blocks with blockIdx.x >= 8 — they fill CUs the 256-block GEMM leaves
// idle). u replaces the colsum kernel: S[p] = (ek[p].u)*kinv[p] analytically.
// ---------------------------------------------------------------------------
__global__ __launch_bounds__(256) void cos_kernel(
    const float* __restrict__ xq, const float* __restrict__ ek,
    const float* __restrict__ rqn, const float* __restrict__ rkn,
    const double* __restrict__ qinv, float* __restrict__ cosm,
    double* __restrict__ u) {
  if (blockIdx.x >= NPOOL / 64) {
    // ---- usum branch: 2*32 = 64 blocks, 32 rows each ----
    int b = (blockIdx.x - NPOOL / 64) * (NB / 64) + blockIdx.y;  // 0..63
    int c0 = threadIdx.x;
    int r0 = b * 32;
    double s0 = 0.0, s1 = 0.0, s2 = 0.0;
    for (int r = r0; r < r0 + 32; r++) {
      double inv = qinv[r];
      const float* xr = xq + (size_t)r * NEMB;
      s0 = fma((double)xr[c0], inv, s0);
      s1 = fma((double)xr[c0 + 256], inv, s1);
      s2 = fma((double)xr[c0 + 512], inv, s2);
    }
    atomicAdd(&u[c0], s0);
    atomicAdd(&u[c0 + 256], s1);
    atomicAdd(&u[c0 + 512], s2);
    return;
  }
  // ---- GEMM branch: cosm[b][p] = (xq[b].ek[p]) * rqn[b] * rkn[p] ----
  __shared__ float As[32][68];
  __shared__ float Bs[32][68];
  const int t = threadIdx.x;
  const int tx = t & 15;   // p-dir, 4 cols each
  const int ty = t >> 4;   // b-dir, 4 rows each
  const int bp = blockIdx.x * 64;
  const int bb = blockIdx.y * 64;
  float acc[4][4] = {};
  for (int k0 = 0; k0 < NEMB; k0 += 32) {
#pragma unroll
    for (int uu = 0; uu < 2; uu++) {
      int uidx = t + uu * 256;       // 0..511
      int m = uidx >> 3;             // 0..63
      int k4 = (uidx & 7) * 4;       // 0..28
      float4 a = *(const float4*)(xq + (size_t)(bb + m) * NEMB + k0 + k4);
      float4 bvv = *(const float4*)(ek + (size_t)(bp + m) * NEMB + k0 + k4);
      As[k4 + 0][m] = a.x; As[k4 + 1][m] = a.y; As[k4 + 2][m] = a.z; As[k4 + 3][m] = a.w;
      Bs[k4 + 0][m] = bvv.x; Bs[k4 + 1][m] = bvv.y; Bs[k4 + 2][m] = bvv.z; Bs[k4 + 3][m] = bvv.w;
    }
    __syncthreads();
#pragma unroll
    for (int kk = 0; kk < 32; kk++) {
      float4 av = *(const float4*)&As[kk][ty * 4];
      float4 bv = *(const float4*)&Bs[kk][tx * 4];
      acc[0][0] = fmaf(av.x, bv.x, acc[0][0]); acc[0][1] = fmaf(av.x, bv.y, acc[0][1]);
      acc[0][2] = fmaf(av.x, bv.z, acc[0][2]); acc[0][3] = fmaf(av.x, bv.w, acc[0][3]);
      acc[1][0] = fmaf(av.y, bv.x, acc[1][0]); acc[1][1] = fmaf(av.y, bv.y, acc[1][1]);
      acc[1][2] = fmaf(av.y, bv.z, acc[1][2]); acc[1][3] = fmaf(av.y, bv.w, acc[1][3]);
      acc[2][0] = fmaf(av.z, bv.x, acc[2][0]); acc[2][1] = fmaf(av.z, bv.y, acc[2][1]);
      acc[2][2] = fmaf(av.z, bv.z, acc[2][2]); acc[2][3] = fmaf(av.z, bv.w, acc[2][3]);
      acc[3][0] = fmaf(av.w, bv.x, acc[3][0]); acc[3][1] = fmaf(av.w, bv.y, acc[3][1]);
      acc[3][2] = fmaf(av.w, bv.z, acc[3][2]); acc[3][3] = fmaf(av.w, bv.w, acc[3][3]);
    }
    __syncthreads();
  }
  float4 rk = *(const float4*)&rkn[bp + tx * 4];
#pragma unroll
  for (int i = 0; i < 4; i++) {
    float rq = rqn[bb + ty * 4 + i];
    float4 cv;
    cv.x = acc[i][0] * rq * rk.x;
    cv.y = acc[i][1] * rq * rk.y;
    cv.z = acc[i][2] * rq * rk.z;
    cv.w = acc[i][3] * rq * rk.w;
    *(float4*)(cosm + (size_t)(bb + ty * 4 + i) * NPOOL + bp + tx * 4) = cv;
  }
}

// ---------------------------------------------------------------------------
// K3: top-4 with fp64 refinement — SEPARATE kernel again (the round-1 fusion
// with gather regressed: VGPR-heavy topk state in the streaming kernel + 3/4
// waves parked during the per-block wave-0 prologue). One wave per row, 4
// rows per block, all waves busy.
// ---------------------------------------------------------------------------
__device__ __forceinline__ bool btf(float av, int ai, float bv, int bi) {
  return (av > bv) || (av == bv && ai < bi);
}
__device__ __forceinline__ bool btd(double av, int ai, double bv, int bi) {
  return (av > bv) || (av == bv && ai < bi);
}
#define CE(a, b)                                                        \
  do {                                                                  \
    if (!btf(v[a], vi[a], v[b], vi[b])) {                               \
      float tv = v[a]; v[a] = v[b]; v[b] = tv;                          \
      int ti = vi[a]; vi[a] = vi[b]; vi[b] = ti;                        \
    }                                                                   \
  } while (0)

__global__ __launch_bounds__(256) void topk_kernel(
    const float* __restrict__ cosm, const float* __restrict__ xq,
    const float* __restrict__ ek, const double* __restrict__ qinv,
    const double* __restrict__ kinv, int* __restrict__ kidx,
    int* __restrict__ counts) {
  int wave = threadIdx.x >> 6, lane = threadIdx.x & 63;
  int row = blockIdx.x * 4 + wave;
  const float* crow = cosm + (size_t)row * NPOOL;
  float v[8]; int vi[8];
#pragma unroll
  for (int j = 0; j < 8; j++) {
    int p = j * 64 + lane;
    v[j] = crow[p];
    vi[j] = p;
  }
  // sort-8 descending (Batcher odd-even mergesort, 19 CEs)
  CE(0,1); CE(2,3); CE(4,5); CE(6,7);
  CE(0,2); CE(1,3); CE(4,6); CE(5,7);
  CE(1,2); CE(5,6);
  CE(0,4); CE(1,5); CE(2,6); CE(3,7);
  CE(2,4); CE(3,5);
  CE(1,2); CE(3,4); CE(5,6);
  // butterfly merge: after 6 rounds every lane holds the global top-8
#pragma unroll
  for (int off = 1; off < 64; off <<= 1) {
    float ov[8]; int oi[8];
#pragma unroll
    for (int m = 0; m < 8; m++) {
      ov[m] = __shfl_xor(v[m], off, 64);
      oi[m] = __shfl_xor(vi[m], off, 64);
    }
    // pairwise top-8 of two sorted-desc lists -> bitonic
#pragma unroll
    for (int m = 0; m < 8; m++) {
      if (!btf(v[m], vi[m], ov[7 - m], oi[7 - m])) { v[m] = ov[7 - m]; vi[m] = oi[7 - m]; }
    }
    // bitonic sort-8 descending (3 stages)
    CE(0,4); CE(1,5); CE(2,6); CE(3,7);
    CE(0,2); CE(1,3); CE(4,6); CE(5,7);
    CE(0,1); CE(2,3); CE(4,5); CE(6,7);
  }
  // fp64 rescore of the 8 candidates (wave-cooperative dot, 12 elems/lane)
  const float* xrow = xq + (size_t)row * NEMB;
  double xr[12];
#pragma unroll
  for (int e = 0; e < 12; e++) xr[e] = (double)xrow[lane * 12 + e];
  double qi = qinv[row];
  double cand[8];
#pragma unroll
  for (int c = 0; c < 8; c++) {
    int pi = vi[c];
    const float* kb = ek + (size_t)pi * NEMB + lane * 12;
    double s = 0.0;
#pragma unroll
    for (int e = 0; e < 12; e++) s = fma(xr[e], (double)kb[e], s);
#pragma unroll
    for (int off = 1; off < 64; off <<= 1) s += __shfl_xor(s, off, 64);
    cand[c] = s * qi * kinv[pi];
  }
  // top-4 of 8 by fp64 (uniform across lanes; lane 0 writes)
  bool used[8] = {false, false, false, false, false, false, false, false};
#pragma unroll
  for (int m = 0; m < NTOPK; m++) {
    int best = -1;
#pragma unroll
    for (int c = 0; c < 8; c++) {
      if (!used[c] && (best < 0 || btd(cand[c], vi[c], cand[best], vi[best]))) best = c;
    }
    used[best] = true;
    if (lane == 0) {
      kidx[row * 4 + m] = vi[best];
      atomicAdd(&counts[vi[best]], 1);
    }
  }
}
#undef CE

// ---------------------------------------------------------------------------
// K4: gather Pk/Pv (float4, coalesced) + fused x_block passthrough.
// Lean streaming kernel (low VGPR, high occupancy — kept separate from topk
// on purpose). slot s<16 -> e_p[idx[s/4]][s%4 (+4 for Pv)]; s>=16 -> g_p.
// ---------------------------------------------------------------------------
__global__ __launch_bounds__(256) void gather_kernel(
    const float* __restrict__ e_p, const float* __restrict__ g_p,
    const int* __restrict__ kidx, const float* __restrict__ x_block,
    float* __restrict__ Pk, float* __restrict__ Pv,
    float* __restrict__ out_xb) {
  int b = blockIdx.x;
  __shared__ int idx[4];
  if (threadIdx.x < 4) idx[threadIdx.x] = kidx[b * 4 + threadIdx.x];
  __syncthreads();
  float4* dk = (float4*)(Pk + (size_t)b * NSLOT * NEMB);
  float4* dv = (float4*)(Pv + (size_t)b * NSLOT * NEMB);
  const int R = NEMB / 4;  // 192 float4 per row
  for (int u = threadIdx.x; u < NSLOT * R; u += 256) {
    int s = u / R;
    int r = u - s * R;
    const float4* sk;
    const float4* sv;
    if (s < 16) {
      int pi = idx[s >> 2];
      int t = s & 3;
      const float* basek = e_p + ((size_t)pi * NEPL + t) * NEMB;
      sk = (const float4*)basek;
      sv = (const float4*)(basek + 4 * NEMB);
    } else {
      sk = (const float4*)(g_p + (size_t)(s - 16) * NEMB);
      sv = (const float4*)(g_p + (size_t)(s - 16 + 4) * NEMB);
    }
    dk[u] = sk[r];
    dv[u] = sv[r];
  }
  // x_block passthrough. out_xb is offset 1 float (mod 4) from 16B alignment
  // (Pk+Pv are mult-of-4 floats, then +1 loss +512 counts => +513).
  // Peel 3 head + 1 tail scalars; float4-store the aligned middle 191 chunks.
  const float* xsrc = x_block + (size_t)b * NEMB;
  float* xdst = out_xb + (size_t)b * NEMB;
  if (threadIdx.x < 3) xdst[threadIdx.x] = xsrc[threadIdx.x];
  if (threadIdx.x == 3) xdst[NEMB - 1] = xsrc[NEMB - 1];
  for (int k = threadIdx.x; k < 191; k += 256) {
    int i = 3 + 4 * k;
    float4 vv = make_float4(xsrc[i], xsrc[i + 1], xsrc[i + 2], xsrc[i + 3]);
    *(float4*)(xdst + i) = vv;  // (513 + 3 + 4k) % 4 == 0 -> 16B aligned
  }
}

// ---------------------------------------------------------------------------
// K5: loss = 1 - (u . w)/(B*B*K),  w[j] = sum_p counts[p]*kinv[p]*ek[p][j].
// 3 blocks of 256 columns; device-scope atomics + done-counter finish.
// Block 0 also emits counts as float.
// ---------------------------------------------------------------------------
__global__ __launch_bounds__(256) void loss_kernel(
    const float* __restrict__ ek, const double* __restrict__ kinv,
    const double* __restrict__ u, const int* __restrict__ counts,
    double* __restrict__ lacc, int* __restrict__ done,
    float* __restrict__ out_loss, float* __restrict__ out_counts) {
  __shared__ double tp[NPOOL];
  for (int p = threadIdx.x; p < NPOOL; p += 256) {
    int c = counts[p];
    tp[p] = (double)c * kinv[p];
    if (blockIdx.x == 0) out_counts[p] = (float)c;
  }
  __syncthreads();
  const int j = blockIdx.x * 256 + threadIdx.x;  // 0..767
  double m = 0.0;
  for (int p = 0; p < NPOOL; p++) m = fma(tp[p], (double)ek[(size_t)p * NEMB + j], m);
  double part = m * u[j];
  for (int off = 32; off > 0; off >>= 1) part += __shfl_down(part, off, 64);
  __shared__ double red[4];
  if ((threadIdx.x & 63) == 0) red[threadIdx.x >> 6] = part;
  __syncthreads();
  if (threadIdx.x == 0) {
    double tot = red[0] + red[1] + red[2] + red[3];
    atomicAdd(lacc, tot);
    __threadfence();
    int d = atomicAdd(done, 1);
    if (d == 2) {  // last block finishes
      double total = atomicAdd(lacc, 0.0);  // device-scope read
      *out_loss = (float)(1.0 - total / (double)((long long)NB * NB * NTOPK));
    }
  }
}

extern "C" void kernel_launch(void* const* d_in, const int* in_sizes, int n_in,
                              void* d_out, int out_size, void* d_ws, size_t ws_size,
                              hipStream_t stream) {
  const float* x_querry = (const float*)d_in[0];
  const float* x_block  = (const float*)d_in[1];
  const float* e_k      = (const float*)d_in[2];
  const float* e_p      = (const float*)d_in[3];
  const float* g_p      = (const float*)d_in[4];
  // d_in[5] = l (scalar 0) — both E- and G-branches always taken.

  // Workspace layout (~4.3 MB)
  double* qinv   = (double*)d_ws;                     // 2048
  double* kinv   = qinv + NB;                         // 512
  double* u      = kinv + NPOOL;                      // 768
  double* lacc   = u + NEMB;                          // 1
  int*    done   = (int*)(lacc + 1);                  // 1 (+1 pad, keeps 8B align)
  float*  rqn    = (float*)(done + 2);                // 2048
  float*  rkn    = rqn + NB;                          // 512
  float*  cosm   = rkn + NPOOL;                       // 2048*512 (16B-aligned)
  int*    kidx   = (int*)(cosm + (size_t)NB * NPOOL); // 8192
  int*    counts = kidx + NB * NTOPK;                 // 512

  // Output layout (floats): Pk | Pv | loss | counts | x_block
  float* out        = (float*)d_out;
  float* Pk         = out;
  float* Pv         = Pk + (size_t)NB * NSLOT * NEMB;
  float* out_loss   = Pv + (size_t)NB * NSLOT * NEMB;
  float* out_counts = out_loss + 1;
  float* out_xb     = out_counts + NPOOL;

  // 5 dispatches (round-0 had 8; round-1's 4-dispatch fusion regressed).
  norms_kernel<<<NB + NPOOL + 1, 256, 0, stream>>>(
      x_querry, e_k, qinv, kinv, rqn, rkn, u, lacc, done, counts);
  cos_kernel<<<dim3(NPOOL / 64 + 2, NB / 64), 256, 0, stream>>>(
      x_querry, e_k, rqn, rkn, qinv, cosm, u);
  topk_kernel<<<NB / 4, 256, 0, stream>>>(
      cosm, x_querry, e_k, qinv, kinv, kidx, counts);
  gather_kernel<<<NB, 256, 0, stream>>>(
      e_p, g_p, kidx, x_block, Pk, Pv, out_xb);
  loss_kernel<<<3, 256, 0, stream>>>(
      e_k, kinv, u, counts, lacc, done, out_loss, out_counts);
}

// Round 3
// 378.743 us; speedup vs baseline: 1.1258x; 1.0923x over previous
//
#include <hip/hip_runtime.h>
#include <math.h>

// Problem constants
static constexpr int NB    = 2048;  // batch
static constexpr int NPOOL = 512;   // e_prompt_pool_size
static constexpr int NTOPK = 4;     // top_k
static constexpr int NEPL  = 8;     // e_prompt_length
static constexpr int NEMB  = 768;   // emb_d / key_dim
static constexpr int NSLOT = 20;    // K*EPL/2 + GPL/2 = 16 + 4

typedef unsigned short u16;
typedef __attribute__((ext_vector_type(8))) short bf16x8;  // 8 bf16 = 4 VGPRs
typedef __attribute__((ext_vector_type(4))) float f32x4;

// ---------------------------------------------------------------------------
// K1: row L2 norms (fp64 for rescore, fp32 reciprocal for GEMM epilogue)
// + NEW: emit split-bf16 planes (hi = RNE-bf16(x), lo = RNE-bf16(x - hi))
// for the MFMA cos GEMM. rows 0..NB-1 -> x_querry, rest -> e_k.
// hi/lo pointers may be null (fallback path) -> uniform branch, skipped.
// ---------------------------------------------------------------------------
__global__ __launch_bounds__(256) void norms_kernel(
    const float* __restrict__ xq, const float* __restrict__ ek,
    double* __restrict__ qn, double* __restrict__ kn,
    float* __restrict__ rqn, float* __restrict__ rkn,
    u16* __restrict__ xqh, u16* __restrict__ xql,
    u16* __restrict__ ekh, u16* __restrict__ ekl) {
  int row = blockIdx.x;
  const float* src;
  double* dst;
  float* rdst;
  u16* hh;
  u16* ll;
  if (row < NB) {
    src = xq + (size_t)row * NEMB; dst = qn + row; rdst = rqn + row;
    hh = xqh ? xqh + (size_t)row * NEMB : nullptr;
    ll = xql ? xql + (size_t)row * NEMB : nullptr;
  } else {
    int r = row - NB;
    src = ek + (size_t)r * NEMB; dst = kn + r; rdst = rkn + r;
    hh = ekh ? ekh + (size_t)r * NEMB : nullptr;
    ll = ekl ? ekl + (size_t)r * NEMB : nullptr;
  }
  double s = 0.0;
  for (int i = threadIdx.x; i < NEMB; i += 256) {
    float a = src[i];
    s += (double)a * (double)a;
    if (hh) {
      // round-to-nearest-even fp32 -> bf16, then residual -> bf16
      unsigned u = __float_as_uint(a);
      unsigned r = u + 0x7fff + ((u >> 16) & 1);
      u16 h = (u16)(r >> 16);
      float hf = __uint_as_float((unsigned)h << 16);
      float res = a - hf;
      unsigned ul = __float_as_uint(res);
      unsigned rl = ul + 0x7fff + ((ul >> 16) & 1);
      hh[i] = h;
      ll[i] = (u16)(rl >> 16);
    }
  }
  for (int off = 32; off > 0; off >>= 1) s += __shfl_down(s, off, 64);
  __shared__ double red[4];
  if ((threadIdx.x & 63) == 0) red[threadIdx.x >> 6] = s;
  __syncthreads();
  if (threadIdx.x == 0) {
    double n = sqrt(red[0] + red[1] + red[2] + red[3]);
    *dst = n;
    *rdst = (float)(1.0 / fmax(n, 1e-12));
  }
}

// ---------------------------------------------------------------------------
// K2 (MFMA path): cosm[b][p] = (xq[b].ek[p]) * rqn[b] * rkn[p] via 3-term
// split-bf16 MFMA: x ~ hi+lo; dot = hi.hi + hi.lo + lo.hi (lo.lo ~ 2^-18,
// dropped; |cos err| <= ~8e-6 by Cauchy-Schwarz, vs ~1e-4 rank gaps).
// No LDS, no barriers: mfma_f32_16x16x32_bf16 A/B fragments (row = lane&15,
// k = (lane>>4)*8 + e) read row-major bf16 rows as fully-coalesced 16B/lane
// loads (lanes i,i+16,i+32,i+48 cover one 64B line). Block = 64x64 output,
// 512 thr = 8 waves: wave w -> m-strip (w&3)*16, n-half (w>>2)*32 (2 tiles).
// 1-deep software pipeline: prefetch k+1 frags before MFMAing k.
// C/D layout (verified m89/m91): col = lane&15, row = (lane>>4)*4 + j.
// ---------------------------------------------------------------------------
__global__ __launch_bounds__(512) void cos_mfma_kernel(
    const u16* __restrict__ xqh, const u16* __restrict__ xql,
    const u16* __restrict__ ekh, const u16* __restrict__ ekl,
    const float* __restrict__ rqn, const float* __restrict__ rkn,
    float* __restrict__ cosm) {
  const int t = threadIdx.x;
  const int lane = t & 63, w = t >> 6;
  const int mw = (w & 3) * 16;   // m-strip within 64-row block
  const int nh = (w >> 2) * 32;  // n-half within 64-col block
  const int bp = blockIdx.x * 64, bb = blockIdx.y * 64;
  const int lr = lane & 15, kg = (lane >> 4) * 8;
  const size_t arow  = (size_t)(bb + mw + lr) * NEMB + kg;
  const size_t brow0 = (size_t)(bp + nh + lr) * NEMB + kg;
  const size_t brow1 = (size_t)(bp + nh + 16 + lr) * NEMB + kg;
  const u16* pah  = xqh + arow;
  const u16* pal  = xql + arow;
  const u16* pb0h = ekh + brow0;
  const u16* pb0l = ekl + brow0;
  const u16* pb1h = ekh + brow1;
  const u16* pb1l = ekl + brow1;
  f32x4 acc0 = {0.f, 0.f, 0.f, 0.f};
  f32x4 acc1 = {0.f, 0.f, 0.f, 0.f};

  bf16x8 ah  = *(const bf16x8*)(pah);
  bf16x8 al  = *(const bf16x8*)(pal);
  bf16x8 b0h = *(const bf16x8*)(pb0h);
  bf16x8 b0l = *(const bf16x8*)(pb0l);
  bf16x8 b1h = *(const bf16x8*)(pb1h);
  bf16x8 b1l = *(const bf16x8*)(pb1l);
#pragma unroll
  for (int ks = 1; ks <= NEMB / 32; ks++) {
    bf16x8 nah, nal, nb0h, nb0l, nb1h, nb1l;
    if (ks < NEMB / 32) {  // compile-time per unrolled iter
      const int o = ks * 32;
      nah  = *(const bf16x8*)(pah + o);
      nal  = *(const bf16x8*)(pal + o);
      nb0h = *(const bf16x8*)(pb0h + o);
      nb0l = *(const bf16x8*)(pb0l + o);
      nb1h = *(const bf16x8*)(pb1h + o);
      nb1l = *(const bf16x8*)(pb1l + o);
    }
    acc0 = __builtin_amdgcn_mfma_f32_16x16x32_bf16(ah, b0h, acc0, 0, 0, 0);
    acc1 = __builtin_amdgcn_mfma_f32_16x16x32_bf16(ah, b1h, acc1, 0, 0, 0);
    acc0 = __builtin_amdgcn_mfma_f32_16x16x32_bf16(ah, b0l, acc0, 0, 0, 0);
    acc1 = __builtin_amdgcn_mfma_f32_16x16x32_bf16(ah, b1l, acc1, 0, 0, 0);
    acc0 = __builtin_amdgcn_mfma_f32_16x16x32_bf16(al, b0h, acc0, 0, 0, 0);
    acc1 = __builtin_amdgcn_mfma_f32_16x16x32_bf16(al, b1h, acc1, 0, 0, 0);
    if (ks < NEMB / 32) {
      ah = nah; al = nal; b0h = nb0h; b0l = nb0l; b1h = nb1h; b1l = nb1l;
    }
  }
  const float rk0 = rkn[bp + nh + lr];
  const float rk1 = rkn[bp + nh + 16 + lr];
  const int r0 = bb + mw + (lane >> 4) * 4;
#pragma unroll
  for (int j = 0; j < 4; j++) {
    const float rq = rqn[r0 + j];
    cosm[(size_t)(r0 + j) * NPOOL + bp + nh + lr]      = acc0[j] * rq * rk0;
    cosm[(size_t)(r0 + j) * NPOOL + bp + nh + 16 + lr] = acc1[j] * rq * rk1;
  }
}

// ---------------------------------------------------------------------------
// K2 (fallback, ws too small): round-0 fp32 vector GEMM, 64x64 tile.
// ---------------------------------------------------------------------------
__global__ __launch_bounds__(256) void cos_kernel(
    const float* __restrict__ xq, const float* __restrict__ ek,
    const float* __restrict__ rqn, const float* __restrict__ rkn,
    float* __restrict__ cosm) {
  __shared__ float As[32][68];
  __shared__ float Bs[32][68];
  const int t = threadIdx.x;
  const int tx = t & 15;
  const int ty = t >> 4;
  const int bp = blockIdx.x * 64;
  const int bb = blockIdx.y * 64;
  float acc[4][4] = {};
  for (int k0 = 0; k0 < NEMB; k0 += 32) {
#pragma unroll
    for (int uu = 0; uu < 2; uu++) {
      int u = t + uu * 256;
      int m = u >> 3;
      int k4 = (u & 7) * 4;
      float4 a = *(const float4*)(xq + (size_t)(bb + m) * NEMB + k0 + k4);
      float4 b = *(const float4*)(ek + (size_t)(bp + m) * NEMB + k0 + k4);
      As[k4 + 0][m] = a.x; As[k4 + 1][m] = a.y; As[k4 + 2][m] = a.z; As[k4 + 3][m] = a.w;
      Bs[k4 + 0][m] = b.x; Bs[k4 + 1][m] = b.y; Bs[k4 + 2][m] = b.z; Bs[k4 + 3][m] = b.w;
    }
    __syncthreads();
#pragma unroll
    for (int kk = 0; kk < 32; kk++) {
      float4 av = *(const float4*)&As[kk][ty * 4];
      float4 bv = *(const float4*)&Bs[kk][tx * 4];
      acc[0][0] = fmaf(av.x, bv.x, acc[0][0]); acc[0][1] = fmaf(av.x, bv.y, acc[0][1]);
      acc[0][2] = fmaf(av.x, bv.z, acc[0][2]); acc[0][3] = fmaf(av.x, bv.w, acc[0][3]);
      acc[1][0] = fmaf(av.y, bv.x, acc[1][0]); acc[1][1] = fmaf(av.y, bv.y, acc[1][1]);
      acc[1][2] = fmaf(av.y, bv.z, acc[1][2]); acc[1][3] = fmaf(av.y, bv.w, acc[1][3]);
      acc[2][0] = fmaf(av.z, bv.x, acc[2][0]); acc[2][1] = fmaf(av.z, bv.y, acc[2][1]);
      acc[2][2] = fmaf(av.z, bv.z, acc[2][2]); acc[2][3] = fmaf(av.z, bv.w, acc[2][3]);
      acc[3][0] = fmaf(av.w, bv.x, acc[3][0]); acc[3][1] = fmaf(av.w, bv.y, acc[3][1]);
      acc[3][2] = fmaf(av.w, bv.z, acc[3][2]); acc[3][3] = fmaf(av.w, bv.w, acc[3][3]);
    }
    __syncthreads();
  }
  float4 rk = *(const float4*)&rkn[bp + tx * 4];
#pragma unroll
  for (int i = 0; i < 4; i++) {
    float rq = rqn[bb + ty * 4 + i];
    float4 cv;
    cv.x = acc[i][0] * rq * rk.x;
    cv.y = acc[i][1] * rq * rk.y;
    cv.z = acc[i][2] * rq * rk.z;
    cv.w = acc[i][3] * rq * rk.w;
    *(float4*)(cosm + (size_t)(bb + ty * 4 + i) * NPOOL + bp + tx * 4) = cv;
  }
}

// ---------------------------------------------------------------------------
// K3: top-4 with fp64 refinement (round-0 form, unchanged). One wave/row.
// Shortlist = fp32 top-8 (sort-8 + butterfly merge); fp64 rescore; pick 4.
// ---------------------------------------------------------------------------
__device__ __forceinline__ bool btf(float av, int ai, float bv, int bi) {
  return (av > bv) || (av == bv && ai < bi);
}
__device__ __forceinline__ bool btd(double av, int ai, double bv, int bi) {
  return (av > bv) || (av == bv && ai < bi);
}
#define CE(a, b)                                                        \
  do {                                                                  \
    if (!btf(v[a], vi[a], v[b], vi[b])) {                               \
      float tv = v[a]; v[a] = v[b]; v[b] = tv;                          \
      int ti = vi[a]; vi[a] = vi[b]; vi[b] = ti;                        \
    }                                                                   \
  } while (0)

__global__ __launch_bounds__(256) void topk_kernel(
    const float* __restrict__ cosm, const float* __restrict__ xq,
    const float* __restrict__ ek, const double* __restrict__ qn,
    const double* __restrict__ kn, int* __restrict__ kidx,
    int* __restrict__ counts) {
  int wave = threadIdx.x >> 6, lane = threadIdx.x & 63;
  int row = blockIdx.x * 4 + wave;
  const float* crow = cosm + (size_t)row * NPOOL;
  float v[8]; int vi[8];
#pragma unroll
  for (int j = 0; j < 8; j++) {
    int p = j * 64 + lane;
    v[j] = crow[p];
    vi[j] = p;
  }
  CE(0,1); CE(2,3); CE(4,5); CE(6,7);
  CE(0,2); CE(1,3); CE(4,6); CE(5,7);
  CE(1,2); CE(5,6);
  CE(0,4); CE(1,5); CE(2,6); CE(3,7);
  CE(2,4); CE(3,5);
  CE(1,2); CE(3,4); CE(5,6);
#pragma unroll
  for (int off = 1; off < 64; off <<= 1) {
    float ov[8]; int oi[8];
#pragma unroll
    for (int m = 0; m < 8; m++) {
      ov[m] = __shfl_xor(v[m], off, 64);
      oi[m] = __shfl_xor(vi[m], off, 64);
    }
#pragma unroll
    for (int m = 0; m < 8; m++) {
      if (!btf(v[m], vi[m], ov[7 - m], oi[7 - m])) { v[m] = ov[7 - m]; vi[m] = oi[7 - m]; }
    }
    CE(0,4); CE(1,5); CE(2,6); CE(3,7);
    CE(0,2); CE(1,3); CE(4,6); CE(5,7);
    CE(0,1); CE(2,3); CE(4,5); CE(6,7);
  }
  const float* xrow = xq + (size_t)row * NEMB;
  double xr[12];
#pragma unroll
  for (int e = 0; e < 12; e++) xr[e] = (double)xrow[lane * 12 + e];
  double qmax = fmax(qn[row], 1e-12);
  double cand[8];
#pragma unroll
  for (int c = 0; c < 8; c++) {
    int pi = vi[c];
    const float* kb = ek + (size_t)pi * NEMB + lane * 12;
    double s = 0.0;
#pragma unroll
    for (int e = 0; e < 12; e++) s = fma(xr[e], (double)kb[e], s);
#pragma unroll
    for (int off = 1; off < 64; off <<= 1) s += __shfl_xor(s, off, 64);
    cand[c] = s / (qmax * fmax(kn[pi], 1e-12));
  }
  bool used[8] = {false, false, false, false, false, false, false, false};
#pragma unroll
  for (int m = 0; m < NTOPK; m++) {
    int best = -1;
#pragma unroll
    for (int c = 0; c < 8; c++) {
      if (!used[c] && (best < 0 || btd(cand[c], vi[c], cand[best], vi[best]))) best = c;
    }
    used[best] = true;
    if (lane == 0) {
      kidx[row * 4 + m] = vi[best];
      atomicAdd(&counts[vi[best]], 1);
    }
  }
}
#undef CE

// ---------------------------------------------------------------------------
// K4: column sums S[p] = sum_b cos[b][p] (fp64 accum over fp32 cosm)
// ---------------------------------------------------------------------------
__global__ __launch_bounds__(256) void colsum_kernel(
    const float* __restrict__ cosm, double* __restrict__ S) {
  int p = blockIdx.x * 256 + threadIdx.x;
  int r0 = blockIdx.y * 128;
  double s = 0.0;
  for (int r = r0; r < r0 + 128; r++) s += (double)cosm[(size_t)r * NPOOL + p];
  atomicAdd(&S[p], s);
}

// ---------------------------------------------------------------------------
// K5: loss = 1 - (sum_p counts[p]*S[p]) / (B*B*K); emit counts as float
// ---------------------------------------------------------------------------
__global__ __launch_bounds__(256) void loss_counts_kernel(
    const double* __restrict__ S, const int* __restrict__ counts,
    float* __restrict__ out_loss, float* __restrict__ out_counts) {
  double s = 0.0;
  for (int p = threadIdx.x; p < NPOOL; p += 256) {
    int c = counts[p];
    out_counts[p] = (float)c;
    s += (double)c * S[p];
  }
  for (int off = 32; off > 0; off >>= 1) s += __shfl_down(s, off, 64);
  __shared__ double red[4];
  if ((threadIdx.x & 63) == 0) red[threadIdx.x >> 6] = s;
  __syncthreads();
  if (threadIdx.x == 0) {
    double total = red[0] + red[1] + red[2] + red[3];
    *out_loss = (float)(1.0 - total / (double)((long long)NB * NB * NTOPK));
  }
}

// ---------------------------------------------------------------------------
// K6: gather Pk/Pv (float4, coalesced) + fused x_block passthrough (float4
// with 3+1 scalar peel for the +513-float misalignment of out_xb).
// ---------------------------------------------------------------------------
__global__ __launch_bounds__(256) void gather_kernel(
    const float* __restrict__ e_p, const float* __restrict__ g_p,
    const int* __restrict__ kidx, const float* __restrict__ x_block,
    float* __restrict__ Pk, float* __restrict__ Pv,
    float* __restrict__ out_xb) {
  int b = blockIdx.x;
  __shared__ int idx[4];
  if (threadIdx.x < 4) idx[threadIdx.x] = kidx[b * 4 + threadIdx.x];
  __syncthreads();
  float4* dk = (float4*)(Pk + (size_t)b * NSLOT * NEMB);
  float4* dv = (float4*)(Pv + (size_t)b * NSLOT * NEMB);
  const int R = NEMB / 4;  // 192 float4 per row
  for (int u = threadIdx.x; u < NSLOT * R; u += 256) {
    int s = u / R;
    int r = u - s * R;
    const float4* sk;
    const float4* sv;
    if (s < 16) {
      int pi = idx[s >> 2];
      int t = s & 3;
      const float* basek = e_p + ((size_t)pi * NEPL + t) * NEMB;
      sk = (const float4*)basek;
      sv = (const float4*)(basek + 4 * NEMB);
    } else {
      sk = (const float4*)(g_p + (size_t)(s - 16) * NEMB);
      sv = (const float4*)(g_p + (size_t)(s - 16 + 4) * NEMB);
    }
    dk[u] = sk[r];
    dv[u] = sv[r];
  }
  const float* xsrc = x_block + (size_t)b * NEMB;
  float* xdst = out_xb + (size_t)b * NEMB;
  if (threadIdx.x < 3) xdst[threadIdx.x] = xsrc[threadIdx.x];
  if (threadIdx.x == 3) xdst[NEMB - 1] = xsrc[NEMB - 1];
  for (int k = threadIdx.x; k < 191; k += 256) {
    int i = 3 + 4 * k;
    float4 vv = make_float4(xsrc[i], xsrc[i + 1], xsrc[i + 2], xsrc[i + 3]);
    *(float4*)(xdst + i) = vv;  // (513 + 3 + 4k) % 4 == 0 -> 16B aligned
  }
}

extern "C" void kernel_launch(void* const* d_in, const int* in_sizes, int n_in,
                              void* d_out, int out_size, void* d_ws, size_t ws_size,
                              hipStream_t stream) {
  const float* x_querry = (const float*)d_in[0];
  const float* x_block  = (const float*)d_in[1];
  const float* e_k      = (const float*)d_in[2];
  const float* e_p      = (const float*)d_in[3];
  const float* g_p      = (const float*)d_in[4];
  // d_in[5] = l (scalar 0) — both E- and G-branches always taken.

  // Workspace layout (round-0 base ~4.3 MB + 7.9 MB bf16 planes = ~12.2 MB)
  double* qn     = (double*)d_ws;                    // 2048
  double* kn     = qn + NB;                          // 512
  double* S      = kn + NPOOL;                       // 512
  float*  rqn    = (float*)(S + NPOOL);              // 2048
  float*  rkn    = rqn + NB;                         // 512
  float*  cosm   = rkn + NPOOL;                      // 2048*512 (16B-aligned)
  int*    kidx   = (int*)(cosm + (size_t)NB * NPOOL);// 8192
  int*    counts = kidx + NB * NTOPK;                // 512
  u16*    xqh    = (u16*)(counts + NPOOL);           // 2048*768 bf16 hi
  u16*    xql    = xqh + (size_t)NB * NEMB;          // 2048*768 bf16 lo
  u16*    ekh    = xql + (size_t)NB * NEMB;          // 512*768 bf16 hi
  u16*    ekl    = ekh + (size_t)NPOOL * NEMB;       // 512*768 bf16 lo
  const size_t ws_need =
      (size_t)((char*)(ekl + (size_t)NPOOL * NEMB) - (char*)d_ws);
  const bool use_mfma = ws_size >= ws_need;

  // Output layout (floats): Pk | Pv | loss | counts | x_block
  float* out        = (float*)d_out;
  float* Pk         = out;
  float* Pv         = Pk + (size_t)NB * NSLOT * NEMB;
  float* out_loss   = Pv + (size_t)NB * NSLOT * NEMB;
  float* out_counts = out_loss + 1;
  float* out_xb     = out_counts + NPOOL;

  hipMemsetAsync(S, 0, NPOOL * sizeof(double), stream);
  hipMemsetAsync(counts, 0, NPOOL * sizeof(int), stream);

  norms_kernel<<<NB + NPOOL, 256, 0, stream>>>(
      x_querry, e_k, qn, kn, rqn, rkn,
      use_mfma ? xqh : nullptr, use_mfma ? xql : nullptr,
      use_mfma ? ekh : nullptr, use_mfma ? ekl : nullptr);
  if (use_mfma) {
    cos_mfma_kernel<<<dim3(NPOOL / 64, NB / 64), 512, 0, stream>>>(
        xqh, xql, ekh, ekl, rqn, rkn, cosm);
  } else {
    cos_kernel<<<dim3(NPOOL / 64, NB / 64), 256, 0, stream>>>(
        x_querry, e_k, rqn, rkn, cosm);
  }
  topk_kernel<<<NB / 4, 256, 0, stream>>>(cosm, x_querry, e_k, qn, kn, kidx, counts);
  colsum_kernel<<<dim3(NPOOL / 256, NB / 128), 256, 0, stream>>>(cosm, S);
  loss_counts_kernel<<<1, 256, 0, stream>>>(S, counts, out_loss, out_counts);
  gather_kernel<<<NB, 256, 0, stream>>>(e_p, g_p, kidx, x_block, Pk, Pv, out_xb);
}

// Round 4
// 368.474 us; speedup vs baseline: 1.1571x; 1.0279x over previous
//
#include <hip/hip_runtime.h>
#include <math.h>

// Problem constants
static constexpr int NB    = 2048;  // batch
static constexpr int NPOOL = 512;   // e_prompt_pool_size
static constexpr int NTOPK = 4;     // top_k
static constexpr int NEPL  = 8;     // e_prompt_length
static constexpr int NEMB  = 768;   // emb_d / key_dim
static constexpr int NSLOT = 20;    // K*EPL/2 + GPL/2 = 16 + 4

typedef unsigned short u16;
typedef __attribute__((ext_vector_type(8))) short bf16x8;  // 8 bf16 = 4 VGPRs
typedef __attribute__((ext_vector_type(4))) float f32x4;

// ---------------------------------------------------------------------------
// K1: row L2 norms (fp64 for rescore, fp32 reciprocal for GEMM epilogue)
// + split-bf16 planes (hi = RNE-bf16(x), lo = RNE-bf16(x - hi)) for the MFMA
// cos GEMM + fused zero-init block (replaces both hipMemsetAsync nodes).
// rows 0..NB-1 -> x_querry, NB..NB+NPOOL-1 -> e_k, last block -> init.
// ---------------------------------------------------------------------------
__global__ __launch_bounds__(256) void norms_kernel(
    const float* __restrict__ xq, const float* __restrict__ ek,
    double* __restrict__ qn, double* __restrict__ kn,
    float* __restrict__ rqn, float* __restrict__ rkn,
    u16* __restrict__ xqh, u16* __restrict__ xql,
    u16* __restrict__ ekh, u16* __restrict__ ekl,
    double* __restrict__ S, int* __restrict__ counts) {
  int row = blockIdx.x;
  if (row == NB + NPOOL) {  // init block (runs each graph replay)
    for (int i = threadIdx.x; i < NPOOL; i += 256) { S[i] = 0.0; counts[i] = 0; }
    return;
  }
  const float* src;
  double* dst;
  float* rdst;
  u16* hh;
  u16* ll;
  if (row < NB) {
    src = xq + (size_t)row * NEMB; dst = qn + row; rdst = rqn + row;
    hh = xqh ? xqh + (size_t)row * NEMB : nullptr;
    ll = xql ? xql + (size_t)row * NEMB : nullptr;
  } else {
    int r = row - NB;
    src = ek + (size_t)r * NEMB; dst = kn + r; rdst = rkn + r;
    hh = ekh ? ekh + (size_t)r * NEMB : nullptr;
    ll = ekl ? ekl + (size_t)r * NEMB : nullptr;
  }
  double s = 0.0;
  for (int i = threadIdx.x; i < NEMB; i += 256) {
    float a = src[i];
    s += (double)a * (double)a;
    if (hh) {
      // round-to-nearest-even fp32 -> bf16, then residual -> bf16
      unsigned u = __float_as_uint(a);
      unsigned r = u + 0x7fff + ((u >> 16) & 1);
      u16 h = (u16)(r >> 16);
      float hf = __uint_as_float((unsigned)h << 16);
      float res = a - hf;
      unsigned ul = __float_as_uint(res);
      unsigned rl = ul + 0x7fff + ((ul >> 16) & 1);
      hh[i] = h;
      ll[i] = (u16)(rl >> 16);
    }
  }
  for (int off = 32; off > 0; off >>= 1) s += __shfl_down(s, off, 64);
  __shared__ double red[4];
  if ((threadIdx.x & 63) == 0) red[threadIdx.x >> 6] = s;
  __syncthreads();
  if (threadIdx.x == 0) {
    double n = sqrt(red[0] + red[1] + red[2] + red[3]);
    *dst = n;
    *rdst = (float)(1.0 / fmax(n, 1e-12));
  }
}

// ---------------------------------------------------------------------------
// K2 (MFMA path, unchanged from round 3): cosm[b][p] = (xq[b].ek[p])*rqn*rkn
// via 3-term split-bf16 MFMA (hi.hi + hi.lo + lo.hi; |cos err| <= ~8e-6 vs
// ~1e-4 rank gaps -> top-8 shortlist membership preserved; fp64 rescore keeps
// kidx bit-identical). No LDS, no barriers; fully-coalesced 16B/lane loads.
// ---------------------------------------------------------------------------
__global__ __launch_bounds__(512) void cos_mfma_kernel(
    const u16* __restrict__ xqh, const u16* __restrict__ xql,
    const u16* __restrict__ ekh, const u16* __restrict__ ekl,
    const float* __restrict__ rqn, const float* __restrict__ rkn,
    float* __restrict__ cosm) {
  const int t = threadIdx.x;
  const int lane = t & 63, w = t >> 6;
  const int mw = (w & 3) * 16;   // m-strip within 64-row block
  const int nh = (w >> 2) * 32;  // n-half within 64-col block
  const int bp = blockIdx.x * 64, bb = blockIdx.y * 64;
  const int lr = lane & 15, kg = (lane >> 4) * 8;
  const size_t arow  = (size_t)(bb + mw + lr) * NEMB + kg;
  const size_t brow0 = (size_t)(bp + nh + lr) * NEMB + kg;
  const size_t brow1 = (size_t)(bp + nh + 16 + lr) * NEMB + kg;
  const u16* pah  = xqh + arow;
  const u16* pal  = xql + arow;
  const u16* pb0h = ekh + brow0;
  const u16* pb0l = ekl + brow0;
  const u16* pb1h = ekh + brow1;
  const u16* pb1l = ekl + brow1;
  f32x4 acc0 = {0.f, 0.f, 0.f, 0.f};
  f32x4 acc1 = {0.f, 0.f, 0.f, 0.f};

  bf16x8 ah  = *(const bf16x8*)(pah);
  bf16x8 al  = *(const bf16x8*)(pal);
  bf16x8 b0h = *(const bf16x8*)(pb0h);
  bf16x8 b0l = *(const bf16x8*)(pb0l);
  bf16x8 b1h = *(const bf16x8*)(pb1h);
  bf16x8 b1l = *(const bf16x8*)(pb1l);
#pragma unroll
  for (int ks = 1; ks <= NEMB / 32; ks++) {
    bf16x8 nah, nal, nb0h, nb0l, nb1h, nb1l;
    if (ks < NEMB / 32) {  // compile-time per unrolled iter
      const int o = ks * 32;
      nah  = *(const bf16x8*)(pah + o);
      nal  = *(const bf16x8*)(pal + o);
      nb0h = *(const bf16x8*)(pb0h + o);
      nb0l = *(const bf16x8*)(pb0l + o);
      nb1h = *(const bf16x8*)(pb1h + o);
      nb1l = *(const bf16x8*)(pb1l + o);
    }
    acc0 = __builtin_amdgcn_mfma_f32_16x16x32_bf16(ah, b0h, acc0, 0, 0, 0);
    acc1 = __builtin_amdgcn_mfma_f32_16x16x32_bf16(ah, b1h, acc1, 0, 0, 0);
    acc0 = __builtin_amdgcn_mfma_f32_16x16x32_bf16(ah, b0l, acc0, 0, 0, 0);
    acc1 = __builtin_amdgcn_mfma_f32_16x16x32_bf16(ah, b1l, acc1, 0, 0, 0);
    acc0 = __builtin_amdgcn_mfma_f32_16x16x32_bf16(al, b0h, acc0, 0, 0, 0);
    acc1 = __builtin_amdgcn_mfma_f32_16x16x32_bf16(al, b1h, acc1, 0, 0, 0);
    if (ks < NEMB / 32) {
      ah = nah; al = nal; b0h = nb0h; b0l = nb0l; b1h = nb1h; b1l = nb1l;
    }
  }
  const float rk0 = rkn[bp + nh + lr];
  const float rk1 = rkn[bp + nh + 16 + lr];
  const int r0 = bb + mw + (lane >> 4) * 4;
#pragma unroll
  for (int j = 0; j < 4; j++) {
    const float rq = rqn[r0 + j];
    cosm[(size_t)(r0 + j) * NPOOL + bp + nh + lr]      = acc0[j] * rq * rk0;
    cosm[(size_t)(r0 + j) * NPOOL + bp + nh + 16 + lr] = acc1[j] * rq * rk1;
  }
}

// ---------------------------------------------------------------------------
// K2 (fallback, ws too small): round-0 fp32 vector GEMM, 64x64 tile.
// ---------------------------------------------------------------------------
__global__ __launch_bounds__(256) void cos_kernel(
    const float* __restrict__ xq, const float* __restrict__ ek,
    const float* __restrict__ rqn, const float* __restrict__ rkn,
    float* __restrict__ cosm) {
  __shared__ float As[32][68];
  __shared__ float Bs[32][68];
  const int t = threadIdx.x;
  const int tx = t & 15;
  const int ty = t >> 4;
  const int bp = blockIdx.x * 64;
  const int bb = blockIdx.y * 64;
  float acc[4][4] = {};
  for (int k0 = 0; k0 < NEMB; k0 += 32) {
#pragma unroll
    for (int uu = 0; uu < 2; uu++) {
      int u = t + uu * 256;
      int m = u >> 3;
      int k4 = (u & 7) * 4;
      float4 a = *(const float4*)(xq + (size_t)(bb + m) * NEMB + k0 + k4);
      float4 b = *(const float4*)(ek + (size_t)(bp + m) * NEMB + k0 + k4);
      As[k4 + 0][m] = a.x; As[k4 + 1][m] = a.y; As[k4 + 2][m] = a.z; As[k4 + 3][m] = a.w;
      Bs[k4 + 0][m] = b.x; Bs[k4 + 1][m] = b.y; Bs[k4 + 2][m] = b.z; Bs[k4 + 3][m] = b.w;
    }
    __syncthreads();
#pragma unroll
    for (int kk = 0; kk < 32; kk++) {
      float4 av = *(const float4*)&As[kk][ty * 4];
      float4 bv = *(const float4*)&Bs[kk][tx * 4];
      acc[0][0] = fmaf(av.x, bv.x, acc[0][0]); acc[0][1] = fmaf(av.x, bv.y, acc[0][1]);
      acc[0][2] = fmaf(av.x, bv.z, acc[0][2]); acc[0][3] = fmaf(av.x, bv.w, acc[0][3]);
      acc[1][0] = fmaf(av.y, bv.x, acc[1][0]); acc[1][1] = fmaf(av.y, bv.y, acc[1][1]);
      acc[1][2] = fmaf(av.y, bv.z, acc[1][2]); acc[1][3] = fmaf(av.y, bv.w, acc[1][3]);
      acc[2][0] = fmaf(av.z, bv.x, acc[2][0]); acc[2][1] = fmaf(av.z, bv.y, acc[2][1]);
      acc[2][2] = fmaf(av.z, bv.z, acc[2][2]); acc[2][3] = fmaf(av.z, bv.w, acc[2][3]);
      acc[3][0] = fmaf(av.w, bv.x, acc[3][0]); acc[3][1] = fmaf(av.w, bv.y, acc[3][1]);
      acc[3][2] = fmaf(av.w, bv.z, acc[3][2]); acc[3][3] = fmaf(av.w, bv.w, acc[3][3]);
    }
    __syncthreads();
  }
  float4 rk = *(const float4*)&rkn[bp + tx * 4];
#pragma unroll
  for (int i = 0; i < 4; i++) {
    float rq = rqn[bb + ty * 4 + i];
    float4 cv;
    cv.x = acc[i][0] * rq * rk.x;
    cv.y = acc[i][1] * rq * rk.y;
    cv.z = acc[i][2] * rq * rk.z;
    cv.w = acc[i][3] * rq * rk.w;
    *(float4*)(cosm + (size_t)(bb + ty * 4 + i) * NPOOL + bp + tx * 4) = cv;
  }
}

// ---------------------------------------------------------------------------
// K3: top-4 with fp64 refinement + FUSED column sums.
// topk already reads every cosm value once; each wave parks its row in an
// LDS slice (plain ds_write, no atomics), one __syncthreads, then 2 fp64
// global atomics per thread replace the whole colsum kernel (saves the
// 4.2 MB cosm re-read + a dispatch). Selection math unchanged (bit-identical
// kidx/counts vs round 3).
// ---------------------------------------------------------------------------
__device__ __forceinline__ bool btf(float av, int ai, float bv, int bi) {
  return (av > bv) || (av == bv && ai < bi);
}
__device__ __forceinline__ bool btd(double av, int ai, double bv, int bi) {
  return (av > bv) || (av == bv && ai < bi);
}
#define CE(a, b)                                                        \
  do {                                                                  \
    if (!btf(v[a], vi[a], v[b], vi[b])) {                               \
      float tv = v[a]; v[a] = v[b]; v[b] = tv;                          \
      int ti = vi[a]; vi[a] = vi[b]; vi[b] = ti;                        \
    }                                                                   \
  } while (0)

__global__ __launch_bounds__(256) void topk_colsum_kernel(
    const float* __restrict__ cosm, const float* __restrict__ xq,
    const float* __restrict__ ek, const double* __restrict__ qn,
    const double* __restrict__ kn, int* __restrict__ kidx,
    int* __restrict__ counts, double* __restrict__ S) {
  __shared__ double colv[4][NPOOL];
  int wave = threadIdx.x >> 6, lane = threadIdx.x & 63;
  int row = blockIdx.x * 4 + wave;
  const float* crow = cosm + (size_t)row * NPOOL;
  float v[8]; int vi[8];
#pragma unroll
  for (int j = 0; j < 8; j++) {
    int p = j * 64 + lane;
    v[j] = crow[p];
    vi[j] = p;
    colv[wave][p] = (double)v[j];
  }
  __syncthreads();
  {  // colsum: 2 columns per thread, 4-row partial then global fp64 atomic
    int c = threadIdx.x;
    double s0 = colv[0][c] + colv[1][c] + colv[2][c] + colv[3][c];
    int c2 = c + 256;
    double s1 = colv[0][c2] + colv[1][c2] + colv[2][c2] + colv[3][c2];
    atomicAdd(&S[c], s0);
    atomicAdd(&S[c2], s1);
  }
  // sort-8 descending (Batcher odd-even mergesort, 19 CEs)
  CE(0,1); CE(2,3); CE(4,5); CE(6,7);
  CE(0,2); CE(1,3); CE(4,6); CE(5,7);
  CE(1,2); CE(5,6);
  CE(0,4); CE(1,5); CE(2,6); CE(3,7);
  CE(2,4); CE(3,5);
  CE(1,2); CE(3,4); CE(5,6);
  // butterfly merge: after 6 rounds every lane holds the global top-8
#pragma unroll
  for (int off = 1; off < 64; off <<= 1) {
    float ov[8]; int oi[8];
#pragma unroll
    for (int m = 0; m < 8; m++) {
      ov[m] = __shfl_xor(v[m], off, 64);
      oi[m] = __shfl_xor(vi[m], off, 64);
    }
#pragma unroll
    for (int m = 0; m < 8; m++) {
      if (!btf(v[m], vi[m], ov[7 - m], oi[7 - m])) { v[m] = ov[7 - m]; vi[m] = oi[7 - m]; }
    }
    CE(0,4); CE(1,5); CE(2,6); CE(3,7);
    CE(0,2); CE(1,3); CE(4,6); CE(5,7);
    CE(0,1); CE(2,3); CE(4,5); CE(6,7);
  }
  // fp64 rescore of the 8 candidates (wave-cooperative dot, 12 elems/lane)
  const float* xrow = xq + (size_t)row * NEMB;
  double xr[12];
#pragma unroll
  for (int e = 0; e < 12; e++) xr[e] = (double)xrow[lane * 12 + e];
  double qmax = fmax(qn[row], 1e-12);
  double cand[8];
#pragma unroll
  for (int c = 0; c < 8; c++) {
    int pi = vi[c];
    const float* kb = ek + (size_t)pi * NEMB + lane * 12;
    double s = 0.0;
#pragma unroll
    for (int e = 0; e < 12; e++) s = fma(xr[e], (double)kb[e], s);
#pragma unroll
    for (int off = 1; off < 64; off <<= 1) s += __shfl_xor(s, off, 64);
    cand[c] = s / (qmax * fmax(kn[pi], 1e-12));
  }
  // top-4 of 8 by fp64 (uniform across lanes; lane 0 writes)
  bool used[8] = {false, false, false, false, false, false, false, false};
#pragma unroll
  for (int m = 0; m < NTOPK; m++) {
    int best = -1;
#pragma unroll
    for (int c = 0; c < 8; c++) {
      if (!used[c] && (best < 0 || btd(cand[c], vi[c], cand[best], vi[best]))) best = c;
    }
    used[best] = true;
    if (lane == 0) {
      kidx[row * 4 + m] = vi[best];
      atomicAdd(&counts[vi[best]], 1);
    }
  }
}
#undef CE

// ---------------------------------------------------------------------------
// K4: gather Pk/Pv + x_block passthrough + FUSED loss/counts finisher
// (block NB). Non-temporal stores on the 252 MB output stream so it doesn't
// evict the L2/L3-resident e_p working set it re-reads 8x.
// ---------------------------------------------------------------------------
__device__ __forceinline__ void nt_store4(float* p, f32x4 v) {
  __builtin_nontemporal_store(v, (f32x4*)p);
}

__global__ __launch_bounds__(256) void gather_loss_kernel(
    const float* __restrict__ e_p, const float* __restrict__ g_p,
    const int* __restrict__ kidx, const float* __restrict__ x_block,
    const double* __restrict__ S, const int* __restrict__ counts,
    float* __restrict__ Pk, float* __restrict__ Pv,
    float* __restrict__ out_xb, float* __restrict__ out_loss,
    float* __restrict__ out_counts) {
  int b = blockIdx.x;
  if (b == NB) {  // loss + counts finisher (S, counts complete after K3)
    double s = 0.0;
    for (int p = threadIdx.x; p < NPOOL; p += 256) {
      int c = counts[p];
      out_counts[p] = (float)c;
      s += (double)c * S[p];
    }
    for (int off = 32; off > 0; off >>= 1) s += __shfl_down(s, off, 64);
    __shared__ double red[4];
    if ((threadIdx.x & 63) == 0) red[threadIdx.x >> 6] = s;
    __syncthreads();
    if (threadIdx.x == 0) {
      double total = red[0] + red[1] + red[2] + red[3];
      *out_loss = (float)(1.0 - total / (double)((long long)NB * NB * NTOPK));
    }
    return;
  }
  __shared__ int idx[4];
  if (threadIdx.x < 4) idx[threadIdx.x] = kidx[b * 4 + threadIdx.x];
  __syncthreads();
  float* dk = Pk + (size_t)b * NSLOT * NEMB;
  float* dv = Pv + (size_t)b * NSLOT * NEMB;
  const int R = NEMB / 4;  // 192 float4 per row
  for (int u = threadIdx.x; u < NSLOT * R; u += 256) {
    int s = u / R;
    int r = u - s * R;
    const f32x4* sk;
    const f32x4* sv;
    if (s < 16) {
      int pi = idx[s >> 2];
      int t = s & 3;
      const float* basek = e_p + ((size_t)pi * NEPL + t) * NEMB;
      sk = (const f32x4*)basek;
      sv = (const f32x4*)(basek + 4 * NEMB);
    } else {
      sk = (const f32x4*)(g_p + (size_t)(s - 16) * NEMB);
      sv = (const f32x4*)(g_p + (size_t)(s - 16 + 4) * NEMB);
    }
    nt_store4(dk + u * 4, sk[r]);
    nt_store4(dv + u * 4, sv[r]);
  }
  // x_block passthrough. out_xb is offset 1 float (mod 4) from 16B alignment
  // (Pk+Pv are mult-of-4 floats, then +1 loss +512 counts => +513).
  // Peel 3 head + 1 tail scalars; nt-float4-store the aligned middle.
  const float* xsrc = x_block + (size_t)b * NEMB;
  float* xdst = out_xb + (size_t)b * NEMB;
  if (threadIdx.x < 3) xdst[threadIdx.x] = xsrc[threadIdx.x];
  if (threadIdx.x == 3) xdst[NEMB - 1] = xsrc[NEMB - 1];
  for (int k = threadIdx.x; k < 191; k += 256) {
    int i = 3 + 4 * k;
    f32x4 vv = {xsrc[i], xsrc[i + 1], xsrc[i + 2], xsrc[i + 3]};
    nt_store4(xdst + i, vv);  // (513 + 3 + 4k) % 4 == 0 -> 16B aligned
  }
}

extern "C" void kernel_launch(void* const* d_in, const int* in_sizes, int n_in,
                              void* d_out, int out_size, void* d_ws, size_t ws_size,
                              hipStream_t stream) {
  const float* x_querry = (const float*)d_in[0];
  const float* x_block  = (const float*)d_in[1];
  const float* e_k      = (const float*)d_in[2];
  const float* e_p      = (const float*)d_in[3];
  const float* g_p      = (const float*)d_in[4];
  // d_in[5] = l (scalar 0) — both E- and G-branches always taken.

  // Workspace layout (round-3 base ~4.3 MB + 7.9 MB bf16 planes = ~12.2 MB)
  double* qn     = (double*)d_ws;                    // 2048
  double* kn     = qn + NB;                          // 512
  double* S      = kn + NPOOL;                       // 512
  float*  rqn    = (float*)(S + NPOOL);              // 2048
  float*  rkn    = rqn + NB;                         // 512
  float*  cosm   = rkn + NPOOL;                      // 2048*512 (16B-aligned)
  int*    kidx   = (int*)(cosm + (size_t)NB * NPOOL);// 8192
  int*    counts = kidx + NB * NTOPK;                // 512
  u16*    xqh    = (u16*)(counts + NPOOL);           // 2048*768 bf16 hi
  u16*    xql    = xqh + (size_t)NB * NEMB;          // 2048*768 bf16 lo
  u16*    ekh    = xql + (size_t)NB * NEMB;          // 512*768 bf16 hi
  u16*    ekl    = ekh + (size_t)NPOOL * NEMB;       // 512*768 bf16 lo
  const size_t ws_need =
      (size_t)((char*)(ekl + (size_t)NPOOL * NEMB) - (char*)d_ws);
  const bool use_mfma = ws_size >= ws_need;

  // Output layout (floats): Pk | Pv | loss | counts | x_block
  float* out        = (float*)d_out;
  float* Pk         = out;
  float* Pv         = Pk + (size_t)NB * NSLOT * NEMB;
  float* out_loss   = Pv + (size_t)NB * NSLOT * NEMB;
  float* out_counts = out_loss + 1;
  float* out_xb     = out_counts + NPOOL;

  // 4 dispatches (round-3 had 8: 2 memsets + 6 kernels).
  norms_kernel<<<NB + NPOOL + 1, 256, 0, stream>>>(
      x_querry, e_k, qn, kn, rqn, rkn,
      use_mfma ? xqh : nullptr, use_mfma ? xql : nullptr,
      use_mfma ? ekh : nullptr, use_mfma ? ekl : nullptr,
      S, counts);
  if (use_mfma) {
    cos_mfma_kernel<<<dim3(NPOOL / 64, NB / 64), 512, 0, stream>>>(
        xqh, xql, ekh, ekl, rqn, rkn, cosm);
  } else {
    cos_kernel<<<dim3(NPOOL / 64, NB / 64), 256, 0, stream>>>(
        x_querry, e_k, rqn, rkn, cosm);
  }
  topk_colsum_kernel<<<NB / 4, 256, 0, stream>>>(
      cosm, x_querry, e_k, qn, kn, kidx, counts, S);
  gather_loss_kernel<<<NB + 1, 256, 0, stream>>>(
      e_p, g_p, kidx, x_block, S, counts, Pk, Pv, out_xb, out_loss, out_counts);
}